// Round 4
// baseline (112.474 us; speedup 1.0000x reference)
//
#include <hip/hip_runtime.h>
#include <math.h>

#define NS 4096
#define NC 500
#define NCP 512        // padded class count for P indexing
#define NF 256
#define NK 400
#define KC_GEMM 16     // split-K chunks (256 rows each)
#define KC_CS   32     // K chunks for colsum (128 rows each)
#define CT 64          // classes per gemm tile
#define NCT 8          // ceil(500/64)
#define NN 16          // n sub-chunk staged in LDS

#define NB_GEMM (NCT * KC_GEMM * 2)       // 256 blocks
#define NB_CS   (KC_CS * 2)               // 64 blocks
#define NB_QUE  ((NC * NF) / 4)           // 32000 blocks (4 waves each)

// ---------------- kernel 1: fused heavy pass ----------------
// blockIdx regions: [0,256) gemm | [256,320) colsum | [320,32320) queue
__global__ __launch_bounds__(256) void k_heavy(
    const float* __restrict__ Xs, const float* __restrict__ Ys, float* __restrict__ Ps,
    const float* __restrict__ Xt, const float* __restrict__ Yt, float* __restrict__ Pt,
    float* __restrict__ CSs, float* __restrict__ CSt,
    const float* __restrict__ queue, const int* __restrict__ qsize,
    float* __restrict__ qsum) {
  // plane-split LDS tiles (even/odd float4 planes -> stride-16B conflict-free reads)
  __shared__ float yA[NN][32], yB[NN][32];
  __shared__ float xA[NN][128], xB[NN][128];
  const int bid = blockIdx.x;

  if (bid < NB_GEMM) {
    // ---- register-tiled GEMM partials: P[kc][c][f] = sum_{n in chunk} Y[n,c]*X[n,f]
    const int z   = bid >> 7;               // 0:src 1:tgt
    const int rem = bid & 127;
    const int kc  = rem >> 3;
    const int ct  = rem & 7;
    const float* X = z ? Xt : Xs;
    const float* Y = z ? Yt : Ys;
    float*       P = z ? Pt : Ps;
    const int c0 = ct * CT;
    const int n0 = kc * (NS / KC_GEMM);
    const int tid = threadIdx.x;
    const int fg = tid & 31;                // feature group: f = fg*8 .. fg*8+7
    const int cg = tid >> 5;                // class group:   c = c0+cg*8 .. +7

    float acc[8][8];
    #pragma unroll
    for (int j = 0; j < 8; ++j)
      #pragma unroll
      for (int k = 0; k < 8; ++k) acc[j][k] = 0.f;

    for (int nn0 = 0; nn0 < NS / KC_GEMM; nn0 += NN) {
      { // stage Y: 16 rows x 64 classes = 256 float4s
        int r = tid >> 4, q = tid & 15;
        int c = c0 + q * 4;
        float4 v = (c < NC) ? *reinterpret_cast<const float4*>(&Y[(size_t)(n0 + nn0 + r) * NC + c])
                            : make_float4(0.f, 0.f, 0.f, 0.f);
        float* dst = (q & 1) ? &yB[r][(q >> 1) * 4] : &yA[r][(q >> 1) * 4];
        *reinterpret_cast<float4*>(dst) = v;
      }
      #pragma unroll
      for (int t = 0; t < 4; ++t) { // stage X: 16 rows x 256 f = 1024 float4s
        int idx = tid + 256 * t;
        int r = idx >> 6, q = idx & 63;
        float4 v = *reinterpret_cast<const float4*>(&X[(size_t)(n0 + nn0 + r) * NF + q * 4]);
        float* dst = (q & 1) ? &xB[r][(q >> 1) * 4] : &xA[r][(q >> 1) * 4];
        *reinterpret_cast<float4*>(dst) = v;
      }
      __syncthreads();

      #pragma unroll 4
      for (int r = 0; r < NN; ++r) {
        float4 y0 = *reinterpret_cast<float4*>(&yA[r][cg * 4]);
        float4 y1 = *reinterpret_cast<float4*>(&yB[r][cg * 4]);
        float4 x0 = *reinterpret_cast<float4*>(&xA[r][fg * 4]);
        float4 x1 = *reinterpret_cast<float4*>(&xB[r][fg * 4]);
        float yv[8] = {y0.x, y0.y, y0.z, y0.w, y1.x, y1.y, y1.z, y1.w};
        float xv[8] = {x0.x, x0.y, x0.z, x0.w, x1.x, x1.y, x1.z, x1.w};
        #pragma unroll
        for (int j = 0; j < 8; ++j)
          #pragma unroll
          for (int k = 0; k < 8; ++k)
            acc[j][k] = fmaf(yv[j], xv[k], acc[j][k]);
      }
      __syncthreads();
    }
    #pragma unroll
    for (int j = 0; j < 8; ++j) {
      int c = c0 + cg * 8 + j;
      if (c < NC) {
        float* dst = &P[((size_t)kc * NCP + c) * NF + fg * 8];
        *reinterpret_cast<float4*>(dst)     = make_float4(acc[j][0], acc[j][1], acc[j][2], acc[j][3]);
        *reinterpret_cast<float4*>(dst + 4) = make_float4(acc[j][4], acc[j][5], acc[j][6], acc[j][7]);
      }
    }

  } else if (bid < NB_GEMM + NB_CS) {
    // ---- column sums: CS[kc][c] = sum_{n in chunk} Y[n,c]
    const int b = bid - NB_GEMM;
    const float* Y = (b >> 5) ? Yt : Ys;
    float*      CS = (b >> 5) ? CSt : CSs;
    const int kc = b & 31;
    const int n0 = kc * (NS / KC_CS);
    const int t  = threadIdx.x;
    float s0 = 0.f, s1 = 0.f;
    for (int n = n0; n < n0 + NS / KC_CS; ++n) {
      const float* row = Y + (size_t)n * NC;
      s0 += row[t];
      if (t + 256 < NC) s1 += row[t + 256];
    }
    CS[kc * 512 + t] = s0;
    if (t + 256 < NC) CS[kc * 512 + t + 256] = s1;

  } else {
    // ---- masked queue reduction with tail-skip: one wave per (c,f) row
    const int qb   = bid - (NB_GEMM + NB_CS);
    const int wave = qb * 4 + (threadIdx.x >> 6);
    const int lane = threadIdx.x & 63;
    const int c    = wave >> 8;                 // NF = 256
    const int qs   = qsize[c];
    const int L    = (qs + 3) >> 2;             // float4s actually needed (<=100)
    const float* base = queue + (size_t)wave * NK;
    float s = 0.f;
    if (lane < L) {
      int k = 4 * lane;                         // 0..255
      float4 v = *reinterpret_cast<const float4*>(base + k);
      s += v.x;                                 // k < qs guaranteed by lane < L
      if (k + 1 < qs) s += v.y;
      if (k + 2 < qs) s += v.z;
      if (k + 3 < qs) s += v.w;
    }
    if (lane + 64 < L) {
      int k = 256 + 4 * lane;                   // 256..399
      float4 v = *reinterpret_cast<const float4*>(base + k);
      s += v.x;
      if (k + 1 < qs) s += v.y;
      if (k + 2 < qs) s += v.z;
      if (k + 3 < qs) s += v.w;
    }
    #pragma unroll
    for (int m = 32; m; m >>= 1) s += __shfl_xor(s, m);
    if (lane == 0) qsum[wave] = s;
  }
}

// ---------------- kernel 2: finalize means + intra diagonal ----------------
__global__ __launch_bounds__(256) void k_means(
    const float* __restrict__ qsum, const int* __restrict__ qsize,
    const float* __restrict__ Psrc, const float* __restrict__ Ptgt,
    const float* __restrict__ CSsrc, const float* __restrict__ CStgt,
    float* __restrict__ MS, float* __restrict__ MT, float* __restrict__ ipart) {
  const int c = blockIdx.x, f = threadIdx.x;
  float cs_s = 0.f, cs_t = 0.f;
  #pragma unroll
  for (int kc = 0; kc < KC_CS; ++kc) {
    cs_s += CSsrc[kc * 512 + c];
    cs_t += CStgt[kc * 512 + c];
  }
  float num = (float)qsize[c];
  float ns = qsum[(size_t)c * NF + f];
  float nt = 0.f;
  #pragma unroll
  for (int kc = 0; kc < KC_GEMM; ++kc) {
    ns += Psrc[((size_t)kc * NCP + c) * NF + f];
    nt += Ptgt[((size_t)kc * NCP + c) * NF + f];
  }
  float ms = ns / (num + cs_s + 1e-8f);
  float mt = nt / (cs_t + 1e-8f);
  MS[(size_t)c * NF + f] = ms;
  MT[(size_t)c * NF + f] = mt;

  float d = ms - mt;
  float s = d * d;
  #pragma unroll
  for (int m = 32; m; m >>= 1) s += __shfl_xor(s, m);
  __shared__ float red[4];
  int wid = f >> 6, lane = f & 63;
  if (lane == 0) red[wid] = s;
  __syncthreads();
  if (f == 0) ipart[c] = sqrtf(fmaxf(red[0] + red[1] + red[2] + red[3], 1e-12f));
}

// ---------------- kernel 3: pairwise distances (16x16 tiles) ----------------
#define TC 16
#define NBT 32                              // ceil(500/16)
__global__ __launch_bounds__(256) void k_dist(const float* __restrict__ MS,
                                              float* __restrict__ epart) {
  __shared__ float a[TC][NF + 4];
  __shared__ float b[TC][NF + 4];
  const int bi = blockIdx.x & (NBT - 1);
  const int bj = blockIdx.x >> 5;

  for (int i = threadIdx.x; i < TC * (NF / 4); i += 256) {
    int r = i >> 6, fq = (i & 63) * 4;
    int c1 = bi * TC + r;
    int c2 = bj * TC + r;
    float4 va = (c1 < NC) ? *reinterpret_cast<const float4*>(&MS[(size_t)c1 * NF + fq])
                          : make_float4(0.f, 0.f, 0.f, 0.f);
    float4 vb = (c2 < NC) ? *reinterpret_cast<const float4*>(&MS[(size_t)c2 * NF + fq])
                          : make_float4(0.f, 0.f, 0.f, 0.f);
    *reinterpret_cast<float4*>(&a[r][fq]) = va;
    *reinterpret_cast<float4*>(&b[r][fq]) = vb;
  }
  __syncthreads();

  const int i1 = threadIdx.x >> 4, i2 = threadIdx.x & 15;
  float s = 0.f;
  #pragma unroll 8
  for (int fq = 0; fq < NF; fq += 4) {
    float4 va = *reinterpret_cast<const float4*>(&a[i1][fq]);
    float4 vb = *reinterpret_cast<const float4*>(&b[i2][fq]);
    float d0 = va.x - vb.x, d1 = va.y - vb.y, d2 = va.z - vb.z, d3 = va.w - vb.w;
    s = fmaf(d0, d0, s); s = fmaf(d1, d1, s); s = fmaf(d2, d2, s); s = fmaf(d3, d3, s);
  }
  bool valid = (bi * TC + i1 < NC) && (bj * TC + i2 < NC);
  float r = valid ? sqrtf(fmaxf(s, 1e-12f)) : 0.f;

  #pragma unroll
  for (int m = 32; m; m >>= 1) r += __shfl_xor(r, m);
  __shared__ float red[4];
  int wid = threadIdx.x >> 6, lane = threadIdx.x & 63;
  if (lane == 0) red[wid] = r;
  __syncthreads();
  if (threadIdx.x == 0) epart[blockIdx.x] = red[0] + red[1] + red[2] + red[3];
}

// ---------------- kernel 4: final scalars ----------------
__global__ __launch_bounds__(1024) void k_final(const float* __restrict__ ipart,
                                                const float* __restrict__ epart,
                                                float* __restrict__ out) {
  const int t = threadIdx.x;                // 1024 threads
  float si = (t < NC) ? ipart[t] : 0.f;
  float se = epart[t];
  #pragma unroll
  for (int m = 32; m; m >>= 1) { si += __shfl_xor(si, m); se += __shfl_xor(se, m); }
  __shared__ float ri[16], re[16];
  int wid = t >> 6, lane = t & 63;
  if (lane == 0) { ri[wid] = si; re[wid] = se; }
  __syncthreads();
  if (t == 0) {
    float A = 0.f, B = 0.f;
    #pragma unroll
    for (int w = 0; w < 16; ++w) { A += ri[w]; B += re[w]; }
    out[0] = A / (float)NC;
    out[1] = B / ((float)NC * (float)NC);
  }
}

extern "C" void kernel_launch(void* const* d_in, const int* in_sizes, int n_in,
                              void* d_out, int out_size, void* d_ws, size_t ws_size,
                              hipStream_t stream) {
  const float* src_x = (const float*)d_in[0];
  const float* tgt_x = (const float*)d_in[1];
  const float* src_y = (const float*)d_in[2];
  const float* tgt_y = (const float*)d_in[3];
  const float* queue = (const float*)d_in[4];
  const int*   qsize = (const int*)d_in[5];
  float* out = (float*)d_out;

  float* ws    = (float*)d_ws;
  float* qsum  = ws;                                   // 128000
  float* Psrc  = qsum + NC * NF;                       // 16 * 512 * 256
  float* Ptgt  = Psrc + (size_t)KC_GEMM * NCP * NF;    // 16 * 512 * 256
  float* CSs   = Ptgt + (size_t)KC_GEMM * NCP * NF;    // 32 * 512
  float* CSt   = CSs + KC_CS * 512;                    // 32 * 512
  float* MS    = CSt + KC_CS * 512;                    // 128000
  float* MT    = MS + NC * NF;                         // 128000
  float* ipart = MT + NC * NF;                         // 500
  float* epart = ipart + NC;                           // 1024

  // 1) fused heavy pass: gemm + colsum + queue reduction
  k_heavy<<<NB_GEMM + NB_CS + NB_QUE, 256, 0, stream>>>(
      src_x, src_y, Psrc, tgt_x, tgt_y, Ptgt, CSs, CSt, queue, qsize, qsum);

  // 2) means + intra diagonal
  k_means<<<NC, 256, 0, stream>>>(qsum, qsize, Psrc, Ptgt, CSs, CSt, MS, MT, ipart);

  // 3) pairwise distances
  k_dist<<<NBT * NBT, 256, 0, stream>>>(MS, epart);

  // 4) final reduction
  k_final<<<1, 1024, 0, stream>>>(ipart, epart, out);
}

// Round 5
// 81.998 us; speedup vs baseline: 1.3717x; 1.3717x over previous
//
#include <hip/hip_runtime.h>
#include <math.h>

#define NS 4096
#define NC 500
#define NF 256
#define NK 400
#define KC_GEMM 16     // split-K chunks (256 rows each)
#define KC_CS   32     // K chunks for colsum (128 rows each)

#define NB_GEMM (32 * KC_GEMM * 2)        // 1024 blocks
#define NB_CS   (KC_CS * 2)               // 64 blocks
#define NB_QUE  ((NC * NF) / 16)          // 8000 blocks (4 waves x 4 rows each)

// ---------------- kernel 1: fused heavy pass ----------------
// blockIdx regions: [0,1024) gemm | [1024,1088) colsum | [1088,9088) queue
// Jobs stress different pipes (VALU / latency / HBM) and overlap.
__global__ __launch_bounds__(256) void k_heavy(
    const float* __restrict__ Xs, const float* __restrict__ Ys, float* __restrict__ Ps,
    const float* __restrict__ Xt, const float* __restrict__ Yt, float* __restrict__ Pt,
    float* __restrict__ CSs, float* __restrict__ CSt,
    const float* __restrict__ queue, const int* __restrict__ qsize,
    float* __restrict__ qsum) {
  __shared__ float ytile[NS / KC_GEMM][16];     // 16 KB (gemm blocks only)
  const int bid = blockIdx.x;

  if (bid < NB_GEMM) {
    // ---- GEMM partials: P[kc][c][f] = sum_{n in chunk} Y[n,c] * X[n,f]
    // (R3-measured structure: ytile reads are wave-uniform -> LDS broadcast, free)
    const int z   = bid >> 9;                   // 0:src 1:tgt
    const int rem = bid & 511;
    const int kc  = rem >> 5;
    const int c0  = (rem & 31) * 16;
    const float* X = z ? Xt : Xs;
    const float* Y = z ? Yt : Ys;
    float*       P = z ? Pt : Ps;
    const int n0   = kc * (NS / KC_GEMM);
    const int cmax = (NC - c0 < 16) ? (NC - c0) : 16;

    for (int i = threadIdx.x; i < (NS / KC_GEMM) * 16; i += 256) {
      int r = i >> 4, cc = i & 15;
      ytile[r][cc] = (cc < cmax) ? Y[(size_t)(n0 + r) * NC + c0 + cc] : 0.f;
    }
    __syncthreads();

    const int f = threadIdx.x;
    float acc[16];
    #pragma unroll
    for (int j = 0; j < 16; ++j) acc[j] = 0.f;

    #pragma unroll 4
    for (int n = 0; n < NS / KC_GEMM; ++n) {
      float xv = X[(size_t)(n0 + n) * NF + f];
      #pragma unroll
      for (int j = 0; j < 16; ++j) acc[j] = fmaf(ytile[n][j], xv, acc[j]);
    }
    #pragma unroll
    for (int j = 0; j < 16; ++j)
      if (c0 + j < NC) P[((size_t)kc * NC + c0 + j) * NF + f] = acc[j];

  } else if (bid < NB_GEMM + NB_CS) {
    // ---- column sums: CS[kc][c] = sum_{n in chunk} Y[n,c]
    const int b = bid - NB_GEMM;
    const float* Y = (b >> 5) ? Yt : Ys;
    float*      CS = (b >> 5) ? CSt : CSs;
    const int kc = b & 31;
    const int n0 = kc * (NS / KC_CS);
    const int t  = threadIdx.x;
    float s0 = 0.f, s1 = 0.f;
    for (int n = n0; n < n0 + NS / KC_CS; ++n) {
      const float* row = Y + (size_t)n * NC;
      s0 += row[t];
      if (t + 256 < NC) s1 += row[t + 256];
    }
    CS[kc * 512 + t] = s0;
    if (t + 256 < NC) CS[kc * 512 + t + 256] = s1;

  } else {
    // ---- masked queue reduction, tail-skip, 4 rows per wave (same class
    //      -> uniform branches; 4-8 independent float4 loads in flight)
    const int qb   = bid - (NB_GEMM + NB_CS);
    const int widx = threadIdx.x >> 6;
    const int lane = threadIdx.x & 63;
    const int r0   = (qb * 4 + widx) * 4;       // 4 consecutive rows
    const int c    = r0 >> 8;                   // NF = 256; same c for all 4
    const int qs   = qsize[c];
    const int L    = (qs + 3) >> 2;             // float4s needed (<=100)
    const float* base = queue + (size_t)r0 * NK;
    float s0 = 0.f, s1 = 0.f, s2 = 0.f, s3 = 0.f;

    if (lane < L) {
      const int k = 4 * lane;                   // 0..255, k < qs guaranteed
      float4 v0 = *reinterpret_cast<const float4*>(base + 0 * NK + k);
      float4 v1 = *reinterpret_cast<const float4*>(base + 1 * NK + k);
      float4 v2 = *reinterpret_cast<const float4*>(base + 2 * NK + k);
      float4 v3 = *reinterpret_cast<const float4*>(base + 3 * NK + k);
      s0 += v0.x; s1 += v1.x; s2 += v2.x; s3 += v3.x;
      if (k + 1 < qs) { s0 += v0.y; s1 += v1.y; s2 += v2.y; s3 += v3.y; }
      if (k + 2 < qs) { s0 += v0.z; s1 += v1.z; s2 += v2.z; s3 += v3.z; }
      if (k + 3 < qs) { s0 += v0.w; s1 += v1.w; s2 += v2.w; s3 += v3.w; }
    }
    if (lane + 64 < L) {
      const int k = 256 + 4 * lane;             // 256..399
      float4 v0 = *reinterpret_cast<const float4*>(base + 0 * NK + k);
      float4 v1 = *reinterpret_cast<const float4*>(base + 1 * NK + k);
      float4 v2 = *reinterpret_cast<const float4*>(base + 2 * NK + k);
      float4 v3 = *reinterpret_cast<const float4*>(base + 3 * NK + k);
      s0 += v0.x; s1 += v1.x; s2 += v2.x; s3 += v3.x;
      if (k + 1 < qs) { s0 += v0.y; s1 += v1.y; s2 += v2.y; s3 += v3.y; }
      if (k + 2 < qs) { s0 += v0.z; s1 += v1.z; s2 += v2.z; s3 += v3.z; }
      if (k + 3 < qs) { s0 += v0.w; s1 += v1.w; s2 += v2.w; s3 += v3.w; }
    }
    #pragma unroll
    for (int m = 32; m; m >>= 1) {
      s0 += __shfl_xor(s0, m); s1 += __shfl_xor(s1, m);
      s2 += __shfl_xor(s2, m); s3 += __shfl_xor(s3, m);
    }
    if (lane == 0)
      *reinterpret_cast<float4*>(&qsum[r0]) = make_float4(s0, s1, s2, s3);
  }
}

// ---------------- kernel 2: finalize means + intra diagonal ----------------
__global__ __launch_bounds__(256) void k_means(
    const float* __restrict__ qsum, const int* __restrict__ qsize,
    const float* __restrict__ Psrc, const float* __restrict__ Ptgt,
    const float* __restrict__ CSsrc, const float* __restrict__ CStgt,
    float* __restrict__ MS, float* __restrict__ MT, float* __restrict__ ipart) {
  const int c = blockIdx.x, f = threadIdx.x;
  float cs_s = 0.f, cs_t = 0.f;
  #pragma unroll
  for (int kc = 0; kc < KC_CS; ++kc) {
    cs_s += CSsrc[kc * 512 + c];
    cs_t += CStgt[kc * 512 + c];
  }
  float num = (float)qsize[c];
  float ns = qsum[(size_t)c * NF + f];
  float nt = 0.f;
  #pragma unroll
  for (int kc = 0; kc < KC_GEMM; ++kc) {
    ns += Psrc[((size_t)kc * NC + c) * NF + f];
    nt += Ptgt[((size_t)kc * NC + c) * NF + f];
  }
  float ms = ns / (num + cs_s + 1e-8f);
  float mt = nt / (cs_t + 1e-8f);
  MS[(size_t)c * NF + f] = ms;
  MT[(size_t)c * NF + f] = mt;

  float d = ms - mt;
  float s = d * d;
  #pragma unroll
  for (int m = 32; m; m >>= 1) s += __shfl_xor(s, m);
  __shared__ float red[4];
  int wid = f >> 6, lane = f & 63;
  if (lane == 0) red[wid] = s;
  __syncthreads();
  if (f == 0) ipart[c] = sqrtf(fmaxf(red[0] + red[1] + red[2] + red[3], 1e-12f));
}

// ---------------- kernel 3: pairwise distances (16x16 tiles) ----------------
#define TC 16
#define NBT 32                              // ceil(500/16)
__global__ __launch_bounds__(256) void k_dist(const float* __restrict__ MS,
                                              float* __restrict__ epart) {
  __shared__ float a[TC][NF + 4];
  __shared__ float b[TC][NF + 4];
  const int bi = blockIdx.x & (NBT - 1);
  const int bj = blockIdx.x >> 5;

  for (int i = threadIdx.x; i < TC * (NF / 4); i += 256) {
    int r = i >> 6, fq = (i & 63) * 4;
    int c1 = bi * TC + r;
    int c2 = bj * TC + r;
    float4 va = (c1 < NC) ? *reinterpret_cast<const float4*>(&MS[(size_t)c1 * NF + fq])
                          : make_float4(0.f, 0.f, 0.f, 0.f);
    float4 vb = (c2 < NC) ? *reinterpret_cast<const float4*>(&MS[(size_t)c2 * NF + fq])
                          : make_float4(0.f, 0.f, 0.f, 0.f);
    *reinterpret_cast<float4*>(&a[r][fq]) = va;
    *reinterpret_cast<float4*>(&b[r][fq]) = vb;
  }
  __syncthreads();

  const int i1 = threadIdx.x >> 4, i2 = threadIdx.x & 15;
  float s = 0.f;
  #pragma unroll 8
  for (int fq = 0; fq < NF; fq += 4) {
    float4 va = *reinterpret_cast<const float4*>(&a[i1][fq]);
    float4 vb = *reinterpret_cast<const float4*>(&b[i2][fq]);
    float d0 = va.x - vb.x, d1 = va.y - vb.y, d2 = va.z - vb.z, d3 = va.w - vb.w;
    s = fmaf(d0, d0, s); s = fmaf(d1, d1, s); s = fmaf(d2, d2, s); s = fmaf(d3, d3, s);
  }
  bool valid = (bi * TC + i1 < NC) && (bj * TC + i2 < NC);
  float r = valid ? sqrtf(fmaxf(s, 1e-12f)) : 0.f;

  #pragma unroll
  for (int m = 32; m; m >>= 1) r += __shfl_xor(r, m);
  __shared__ float red[4];
  int wid = threadIdx.x >> 6, lane = threadIdx.x & 63;
  if (lane == 0) red[wid] = r;
  __syncthreads();
  if (threadIdx.x == 0) epart[blockIdx.x] = red[0] + red[1] + red[2] + red[3];
}

// ---------------- kernel 4: final scalars ----------------
__global__ __launch_bounds__(1024) void k_final(const float* __restrict__ ipart,
                                                const float* __restrict__ epart,
                                                float* __restrict__ out) {
  const int t = threadIdx.x;                // 1024 threads
  float si = (t < NC) ? ipart[t] : 0.f;
  float se = epart[t];
  #pragma unroll
  for (int m = 32; m; m >>= 1) { si += __shfl_xor(si, m); se += __shfl_xor(se, m); }
  __shared__ float ri[16], re[16];
  int wid = t >> 6, lane = t & 63;
  if (lane == 0) { ri[wid] = si; re[wid] = se; }
  __syncthreads();
  if (t == 0) {
    float A = 0.f, B = 0.f;
    #pragma unroll
    for (int w = 0; w < 16; ++w) { A += ri[w]; B += re[w]; }
    out[0] = A / (float)NC;
    out[1] = B / ((float)NC * (float)NC);
  }
}

extern "C" void kernel_launch(void* const* d_in, const int* in_sizes, int n_in,
                              void* d_out, int out_size, void* d_ws, size_t ws_size,
                              hipStream_t stream) {
  const float* src_x = (const float*)d_in[0];
  const float* tgt_x = (const float*)d_in[1];
  const float* src_y = (const float*)d_in[2];
  const float* tgt_y = (const float*)d_in[3];
  const float* queue = (const float*)d_in[4];
  const int*   qsize = (const int*)d_in[5];
  float* out = (float*)d_out;

  float* ws    = (float*)d_ws;
  float* qsum  = ws;                                   // 128000
  float* Psrc  = qsum + NC * NF;                       // 16 * 128000
  float* Ptgt  = Psrc + (size_t)KC_GEMM * NC * NF;     // 16 * 128000
  float* CSs   = Ptgt + (size_t)KC_GEMM * NC * NF;     // 32 * 512
  float* CSt   = CSs + KC_CS * 512;                    // 32 * 512
  float* MS    = CSt + KC_CS * 512;                    // 128000
  float* MT    = MS + NC * NF;                         // 128000
  float* ipart = MT + NC * NF;                         // 500
  float* epart = ipart + NC;                           // 1024

  // 1) fused heavy pass: gemm + colsum + queue reduction
  k_heavy<<<NB_GEMM + NB_CS + NB_QUE, 256, 0, stream>>>(
      src_x, src_y, Psrc, tgt_x, tgt_y, Ptgt, CSs, CSt, queue, qsize, qsum);

  // 2) means + intra diagonal
  k_means<<<NC, 256, 0, stream>>>(qsum, qsize, Psrc, Ptgt, CSs, CSt, MS, MT, ipart);

  // 3) pairwise distances
  k_dist<<<NBT * NBT, 256, 0, stream>>>(MS, epart);

  // 4) final reduction
  k_final<<<1, 1024, 0, stream>>>(ipart, epart, out);
}